// Round 13
// baseline (315.734 us; speedup 1.0000x reference)
//
#include <hip/hip_runtime.h>
#include <hip/hip_bf16.h>

// ============ MEASUREMENT ROUND: rep-amplified kernels =====================
// Each kernel body repeats R times (idempotent) so per-kernel dispatches
// exceed the ~42us harness fills and appear in rocprof top-5.
// True per-kernel time = dur_us / R.  Config otherwise == round 9 (41.1us).
#define R_CVT 32
#define R_G1  12
#define R_G2  8

typedef __attribute__((ext_vector_type(8))) short short8;
typedef __attribute__((ext_vector_type(4))) float f32x4;

#define NTOK 4096
#define DIN  1024
#define DOUT 1024
#define KTOT 1152
#define XLD  1152
#define TLDS 200

__device__ __forceinline__ unsigned short f2bf(float f) {
    __hip_bfloat16 h = __float2bfloat16(f);
    return __builtin_bit_cast(unsigned short, h);
}

__device__ __forceinline__ void gload16(const void* g, void* l) {
    __builtin_amdgcn_global_load_lds((const __attribute__((address_space(1))) void*)g,
                                     (__attribute__((address_space(3))) void*)l, 16, 0, 0);
}

__device__ __forceinline__ uint4 pack2(float4 v0, float4 v1) {
    union { unsigned short u[8]; uint4 q; } pk;
    pk.u[0] = f2bf(v0.x); pk.u[1] = f2bf(v0.y); pk.u[2] = f2bf(v0.z); pk.u[3] = f2bf(v0.w);
    pk.u[4] = f2bf(v1.x); pk.u[5] = f2bf(v1.y); pk.u[6] = f2bf(v1.z); pk.u[7] = f2bf(v1.w);
    return pk.q;
}

__device__ __forceinline__ uint4 pack8(const float* s) {
    return pack2(*(const float4*)s, *(const float4*)(s + 4));
}

// ---- weight prep (rep-amplified x32) ---------------------------------------
__global__ __launch_bounds__(256) void k_cvtuw(const float* __restrict__ lora_U,
                                               const float* __restrict__ gate_w,
                                               const float* __restrict__ w,
                                               const float* __restrict__ lora_V,
                                               __hip_bfloat16* __restrict__ Ucat,
                                               __hip_bfloat16* __restrict__ Wcat) {
    for (int rep = 0; rep < R_CVT; ++rep) {
        int b = blockIdx.x;
        if (b < 96) {
            int idx = b * 256 + threadIdx.x;
            int r = idx >> 7, g = idx & 127;
            uint4 q = make_uint4(0u, 0u, 0u, 0u);
            if (r < 128)      q = pack8(lora_U + (size_t)r * DIN + g * 8);
            else if (r < 136) q = pack8(gate_w + (size_t)(r - 128) * DIN + g * 8);
            *(uint4*)(Ucat + (size_t)r * DIN + g * 8) = q;
        } else {
            int idx = (b - 96) * 256 + threadIdx.x;
            int o = idx / 144, g = idx - o * 144;
            const float* s;
            if (g < 128) s = w + (size_t)o * DIN + g * 8;
            else {
                int i0 = (g - 128) * 8;
                int e = i0 >> 4, r = i0 & 15;
                s = lora_V + (size_t)e * (DOUT * 16) + (size_t)o * 16 + r;
            }
            *(uint4*)(Wcat + (size_t)o * KTOT + g * 8) = pack8(s);
        }
    }
}

// ---- GEMM1 fused (rep-amplified x12), round-9 body -------------------------
__global__ __launch_bounds__(256) void k_gemm1f(const float* __restrict__ x,
                                                const __hip_bfloat16* __restrict__ Ucat,
                                                __hip_bfloat16* __restrict__ Xcat) {
    __shared__ char smem[53248];
    float (*Tsm)[TLDS] = (float(*)[TLDS])smem;

    const int t = threadIdx.x, lane = t & 63, wid = t >> 6;
    const int row0 = blockIdx.x * 16;
    const int l7 = lane & 7, l8 = lane >> 3, l15 = lane & 15, l16 = lane >> 4;
    const int scol = ((l7 ^ l8) << 3);

    const int ar = (t & 127) >> 3;
    const int ac8 = (t & 7) * 8;
    const int abyte = ar * 128 + (((t & 7) ^ (ar & 7)) << 4);

    int boff[3];
#pragma unroll
    for (int n = 0; n < 3; ++n) boff[n] = (wid * 48 + n * 16 + l15) * 128;
    const int aoff = l15 * 128;
    int sw[2];
#pragma unroll
    for (int ks = 0; ks < 2; ++ks) sw[ks] = (((ks * 4 + l16) ^ l7) << 4);

    for (int rep = 0; rep < R_G1; ++rep) {
        f32x4 acc[3];
#pragma unroll
        for (int n = 0; n < 3; ++n) acc[n] = (f32x4){0.f, 0.f, 0.f, 0.f};

        // prologue: stage kt=0 into buf0
        if (t < 128) {
            uint4 q = pack8(x + (size_t)(row0 + ar) * DIN + 0 + ac8);
            *(uint4*)(smem + 0 * 2048 + abyte) = q;
            *(uint4*)(Xcat + (size_t)(row0 + ar) * XLD + 0 + ac8) = q;
        }
#pragma unroll
        for (int i = 0; i < 6; ++i) {
            int cj = wid * 6 + i;
            gload16(Ucat + (size_t)(cj * 8 + l8) * DIN + 0 + scol,
                    smem + 4096 + cj * 1024);
        }
        __syncthreads();

        int cur = 0;
        for (int kt = 0; kt < 16; ++kt) {
            const bool hasNext = kt < 15;
            const int k1 = (kt + 1) << 6;
            float4 f0, f1;
            if (hasNext && t < 128) {
                const float* s = x + (size_t)(row0 + ar) * DIN + k1 + ac8;
                f0 = *(const float4*)s; f1 = *(const float4*)(s + 4);
            }
            if (hasNext) {
#pragma unroll
                for (int i = 0; i < 6; ++i) {
                    int cj = wid * 6 + i;
                    gload16(Ucat + (size_t)(cj * 8 + l8) * DIN + k1 + scol,
                            smem + 4096 + (cur ^ 1) * 24576 + cj * 1024);
                }
            }
            const char* Ab = smem + cur * 2048;
            const char* Bb = smem + 4096 + cur * 24576;
#pragma unroll
            for (int ks = 0; ks < 2; ++ks) {
                short8 af = *(const short8*)(Ab + aoff + sw[ks]);
#pragma unroll
                for (int n = 0; n < 3; ++n) {
                    short8 bf = *(const short8*)(Bb + boff[n] + sw[ks]);
                    acc[n] = __builtin_amdgcn_mfma_f32_16x16x32_bf16(af, bf, acc[n], 0, 0, 0);
                }
            }
            if (hasNext && t < 128) {
                uint4 q = pack2(f0, f1);
                *(uint4*)(smem + (cur ^ 1) * 2048 + abyte) = q;
                *(uint4*)(Xcat + (size_t)(row0 + ar) * XLD + k1 + ac8) = q;
            }
            __syncthreads();
            cur ^= 1;
        }

#pragma unroll
        for (int n = 0; n < 3; ++n)
#pragma unroll
            for (int j = 0; j < 4; ++j)
                Tsm[l16 * 4 + j][wid * 48 + n * 16 + l15] = acc[n][j];
        __syncthreads();

        if (t < 128) {
            const int tok = t >> 3, e = t & 7;
            float l[8];
#pragma unroll
            for (int i = 0; i < 8; ++i) l[i] = Tsm[tok][128 + i];
            float m = l[0];
#pragma unroll
            for (int i = 1; i < 8; ++i) m = fmaxf(m, l[i]);
            float s = 0.f;
#pragma unroll
            for (int i = 0; i < 8; ++i) s += __expf(l[i] - m);
            const float g = __expf(l[e] - m) / s * 0.0625f;
            union { unsigned short u[16]; uint4 q[2]; } pk;
#pragma unroll
            for (int jj = 0; jj < 16; ++jj) pk.u[jj] = f2bf(g * Tsm[tok][e * 16 + jj]);
            uint4* dst = (uint4*)(Xcat + (size_t)(row0 + tok) * XLD + 1024 + e * 16);
            dst[0] = pk.q[0]; dst[1] = pk.q[1];
        }
        __syncthreads();   // Tsm/smem handoff before next rep restages
    }
}

// ---- GEMM2 (rep-amplified x8), round-9 body: 128x64, grid 512, 2-phase -----
__global__ __launch_bounds__(256) void k_gemm2(const __hip_bfloat16* __restrict__ A,
                                               const __hip_bfloat16* __restrict__ B,
                                               float* __restrict__ out) {
    __shared__ char smem[49152];
    const int b = blockIdx.x;
    const int xcd = b & 7, j = b >> 3;
    const int bx = xcd * 4 + (j & 3), by = j >> 2;
    const int row0 = bx * 128, col0 = by * 64;

    const int t = threadIdx.x, lane = t & 63, wid = t >> 6;
    const int wr = wid >> 1, wc = wid & 1;
    const int l7 = lane & 7, l8 = lane >> 3, l15 = lane & 15, l16 = lane >> 4;
    const int scol = ((l7 ^ l8) << 3);

    int aoff[4], boff[2], sw[2];
#pragma unroll
    for (int m = 0; m < 4; ++m) aoff[m] = (wr * 64 + m * 16 + l15) * 128;
#pragma unroll
    for (int n = 0; n < 2; ++n) boff[n] = (wc * 32 + n * 16 + l15) * 128;
#pragma unroll
    for (int ks = 0; ks < 2; ++ks) sw[ks] = (((ks * 4 + l16) ^ l7) << 4);

#define G2_STAGE(buf, kt)                                                      \
    {                                                                          \
        const int k0_ = (kt) << 6;                                             \
        _Pragma("unroll")                                                      \
        for (int i = 0; i < 4; ++i) {                                          \
            int ci = wid * 4 + i;                                              \
            gload16(A + (size_t)(row0 + ci * 8 + l8) * XLD + k0_ + scol,       \
                    smem + (buf) * 16384 + ci * 1024);                         \
        }                                                                      \
        _Pragma("unroll")                                                      \
        for (int i = 0; i < 2; ++i) {                                          \
            int cj = wid * 2 + i;                                              \
            gload16(B + (size_t)(col0 + cj * 8 + l8) * KTOT + k0_ + scol,      \
                    smem + 32768 + (buf) * 8192 + cj * 1024);                  \
        }                                                                      \
    }

#define G2_COMP(buf)                                                           \
    {                                                                          \
        const char* Ab = smem + (buf) * 16384;                                 \
        const char* Bb = smem + 32768 + (buf) * 8192;                          \
        _Pragma("unroll")                                                      \
        for (int ks = 0; ks < 2; ++ks) {                                       \
            short8 af[4], bf[2];                                               \
            _Pragma("unroll")                                                  \
            for (int m = 0; m < 4; ++m)                                        \
                af[m] = *(const short8*)(Ab + aoff[m] + sw[ks]);               \
            _Pragma("unroll")                                                  \
            for (int n = 0; n < 2; ++n)                                        \
                bf[n] = *(const short8*)(Bb + boff[n] + sw[ks]);               \
            _Pragma("unroll")                                                  \
            for (int m = 0; m < 4; ++m)                                        \
                _Pragma("unroll")                                              \
                for (int n = 0; n < 2; ++n)                                    \
                    acc[m][n] = __builtin_amdgcn_mfma_f32_16x16x32_bf16(       \
                        af[m], bf[n], acc[m][n], 0, 0, 0);                     \
        }                                                                      \
    }

    for (int rep = 0; rep < R_G2; ++rep) {
        f32x4 zf = {0.f, 0.f, 0.f, 0.f};
        f32x4 acc[4][2];
#pragma unroll
        for (int m = 0; m < 4; ++m)
#pragma unroll
            for (int n = 0; n < 2; ++n) acc[m][n] = zf;

        G2_STAGE(0, 0);
        __syncthreads();
        int cur = 0;
        for (int kt = 0; kt < 17; ++kt) {
            G2_STAGE(cur ^ 1, kt + 1);
            G2_COMP(cur);
            __syncthreads();
            cur ^= 1;
        }
        G2_COMP(cur);

#pragma unroll
        for (int m = 0; m < 4; ++m)
#pragma unroll
            for (int n = 0; n < 2; ++n)
#pragma unroll
                for (int jj = 0; jj < 4; ++jj)
                    out[(size_t)(row0 + wr * 64 + m * 16 + l16 * 4 + jj) * DOUT
                        + col0 + wc * 32 + n * 16 + l15] = acc[m][n][jj];
        __syncthreads();   // all reads of buf1 done before next rep restages
    }
#undef G2_STAGE
#undef G2_COMP
}

extern "C" void kernel_launch(void* const* d_in, const int* in_sizes, int n_in,
                              void* d_out, int out_size, void* d_ws, size_t ws_size,
                              hipStream_t stream) {
    const float* x      = (const float*)d_in[0];
    const float* weight = (const float*)d_in[1];
    const float* gate_w = (const float*)d_in[2];
    const float* lora_U = (const float*)d_in[3];
    const float* lora_V = (const float*)d_in[4];
    float* out = (float*)d_out;

    char* ws = (char*)d_ws;
    __hip_bfloat16* Xcat = (__hip_bfloat16*)ws;
    __hip_bfloat16* Ucat = (__hip_bfloat16*)(ws + 9437184);
    __hip_bfloat16* Wcat = (__hip_bfloat16*)(ws + 9437184 + 393216);

    k_cvtuw<<<672, 256, 0, stream>>>(lora_U, gate_w, weight, lora_V, Ucat, Wcat);
    k_gemm1f<<<256, 256, 0, stream>>>(x, Ucat, Xcat);
    k_gemm2<<<512, 256, 0, stream>>>(Xcat, Wcat, out);
}

// Round 14
// 38.288 us; speedup vs baseline: 8.2462x; 8.2462x over previous
//
#include <hip/hip_runtime.h>
#include <hip/hip_bf16.h>

typedef __attribute__((ext_vector_type(8))) short short8;
typedef __attribute__((ext_vector_type(4))) float f32x4;

#define NTOK 4096
#define DIN  1024
#define DOUT 1024
#define KTOT 1152   // 1024 (W) + 128 (LoRA)
#define XLD  1152
#define TLDS 200    // Tsm leading dim (f32)

__device__ __forceinline__ unsigned short f2bf(float f) {
    __hip_bfloat16 h = __float2bfloat16(f);
    return __builtin_bit_cast(unsigned short, h);
}

__device__ __forceinline__ void gload16(const void* g, void* l) {
    __builtin_amdgcn_global_load_lds((const __attribute__((address_space(1))) void*)g,
                                     (__attribute__((address_space(3))) void*)l, 16, 0, 0);
}

__device__ __forceinline__ uint4 pack8(const float* s) {
    float4 v0 = *(const float4*)s, v1 = *(const float4*)(s + 4);
    union { unsigned short u[8]; uint4 q; } pk;
    pk.u[0] = f2bf(v0.x); pk.u[1] = f2bf(v0.y); pk.u[2] = f2bf(v0.z); pk.u[3] = f2bf(v0.w);
    pk.u[4] = f2bf(v1.x); pk.u[5] = f2bf(v1.y); pk.u[6] = f2bf(v1.z); pk.u[7] = f2bf(v1.w);
    return pk.q;
}

// ---- prep: x -> Xcat[:, :1024] bf16; Ucat = [lora_U;gate_w;0]; Wcat = [W|V2]
// grid 2048 (x) + 672 (weights) = 2720 blocks x 256
__global__ __launch_bounds__(256) void k_cvtuw(const float* __restrict__ x,
                                               const float* __restrict__ lora_U,
                                               const float* __restrict__ gate_w,
                                               const float* __restrict__ w,
                                               const float* __restrict__ lora_V,
                                               __hip_bfloat16* __restrict__ Xcat,
                                               __hip_bfloat16* __restrict__ Ucat,
                                               __hip_bfloat16* __restrict__ Wcat) {
    int b = blockIdx.x;
    if (b < 2048) {                               // x f32 -> Xcat bf16
        int idx = b * 256 + threadIdx.x;          // 4096 rows x 128 groups
        int n = idx >> 7, g = idx & 127;
        *(uint4*)(Xcat + (size_t)n * XLD + g * 8) = pack8(x + (size_t)n * DIN + g * 8);
    } else if (b < 2144) {                        // Ucat (96 blocks)
        int idx = (b - 2048) * 256 + threadIdx.x; // 192 rows x 128 groups
        int r = idx >> 7, g = idx & 127;
        uint4 q = make_uint4(0u, 0u, 0u, 0u);
        if (r < 128)      q = pack8(lora_U + (size_t)r * DIN + g * 8);
        else if (r < 136) q = pack8(gate_w + (size_t)(r - 128) * DIN + g * 8);
        *(uint4*)(Ucat + (size_t)r * DIN + g * 8) = q;
    } else {                                      // Wcat (576 blocks)
        int idx = (b - 2144) * 256 + threadIdx.x; // 1024 rows x 144 groups
        int o = idx / 144, g = idx - o * 144;
        const float* s;
        if (g < 128) s = w + (size_t)o * DIN + g * 8;
        else {
            int i0 = (g - 128) * 8;
            int e = i0 >> 4, r = i0 & 15;
            s = lora_V + (size_t)e * (DOUT * 16) + (size_t)o * 16 + r;
        }
        *(uint4*)(Wcat + (size_t)o * KTOT + g * 8) = pack8(s);
    }
}

// ---- GEMM1 fused: T = Xcat[:,:1024] @ Ucat^T, softmax, coef -> Xcat[:,1024:]
// BM=16, BN=192, BK=64, 256 thr = 4 waves, grid 256. T4 counted-vmcnt pipeline:
// A (2KB) direct-to-reg bf16; B (24KB) via 6 gload_lds/wave; vmcnt(10) keeps
// next tile's 8 newest loads in flight across raw barriers.
__global__ __launch_bounds__(256) void k_gemm1f(const __hip_bfloat16* __restrict__ Xc,
                                                const __hip_bfloat16* __restrict__ Ucat,
                                                __hip_bfloat16* __restrict__ Xcat) {
    __shared__ char smem[49152];                   // B dbuf: 2 x 24KB; Tsm reuse
    float (*Tsm)[TLDS] = (float(*)[TLDS])smem;

    const int t = threadIdx.x, lane = t & 63, wid = t >> 6;
    const int row0 = blockIdx.x * 16;
    const int l7 = lane & 7, l8 = lane >> 3, l15 = lane & 15, l16 = lane >> 4;
    const int scol = ((l7 ^ l8) << 3);             // pre-swizzled global col (B)

    f32x4 acc[3];
#pragma unroll
    for (int n = 0; n < 3; ++n) acc[n] = (f32x4){0.f, 0.f, 0.f, 0.f};

    int boff[3];
#pragma unroll
    for (int n = 0; n < 3; ++n) boff[n] = (wid * 48 + n * 16 + l15) * 128;
    int sw[2];
#pragma unroll
    for (int ks = 0; ks < 2; ++ks) sw[ks] = (((ks * 4 + l16) ^ l7) << 4);

    const __hip_bfloat16* arow = Xc + (size_t)(row0 + l15) * XLD + l16 * 8;
    short8 areg[2][2];                             // [kt&1][ks], static after unroll

    // prologue: issue B(0) then A(0)
#pragma unroll
    for (int i = 0; i < 6; ++i) {
        int cj = wid * 6 + i;
        gload16(Ucat + (size_t)(cj * 8 + l8) * DIN + 0 + scol, smem + cj * 1024);
    }
    areg[0][0] = *(const short8*)(arow + 0);
    areg[0][1] = *(const short8*)(arow + 32);

#pragma unroll
    for (int kt = 0; kt < 16; ++kt) {
        const int cur = kt & 1;
        if (kt < 15) {
            const int k1 = (kt + 1) << 6;
#pragma unroll
            for (int i = 0; i < 6; ++i) {          // B(kt+1) -> other buffer
                int cj = wid * 6 + i;
                gload16(Ucat + (size_t)(cj * 8 + l8) * DIN + k1 + scol,
                        smem + (cur ^ 1) * 24576 + cj * 1024);
            }
            areg[(kt + 1) & 1][0] = *(const short8*)(arow + k1);
            areg[(kt + 1) & 1][1] = *(const short8*)(arow + k1 + 32);
            asm volatile("s_waitcnt vmcnt(10)" ::: "memory");  // drain B(kt) only
        } else {
            asm volatile("s_waitcnt vmcnt(2)" ::: "memory");   // drain last B
        }
        __builtin_amdgcn_s_barrier();
        const char* Bb = smem + cur * 24576;
#pragma unroll
        for (int ks = 0; ks < 2; ++ks) {
            short8 af = areg[cur][ks];
#pragma unroll
            for (int n = 0; n < 3; ++n) {
                short8 bf = *(const short8*)(Bb + boff[n] + sw[ks]);
                acc[n] = __builtin_amdgcn_mfma_f32_16x16x32_bf16(af, bf, acc[n], 0, 0, 0);
            }
        }
        __builtin_amdgcn_s_barrier();              // protect buf before restage
    }

    // acc -> Tsm (f32), C/D mapping col=lane&15, row=(lane>>4)*4+j
#pragma unroll
    for (int n = 0; n < 3; ++n)
#pragma unroll
        for (int j = 0; j < 4; ++j)
            Tsm[l16 * 4 + j][wid * 48 + n * 16 + l15] = acc[n][j];
    __syncthreads();

    // softmax + coef: 8 threads per token (16 tokens x 8 experts)
    if (t < 128) {
        const int tok = t >> 3, e = t & 7;
        float l[8];
#pragma unroll
        for (int i = 0; i < 8; ++i) l[i] = Tsm[tok][128 + i];
        float m = l[0];
#pragma unroll
        for (int i = 1; i < 8; ++i) m = fmaxf(m, l[i]);
        float s = 0.f;
#pragma unroll
        for (int i = 0; i < 8; ++i) s += __expf(l[i] - m);
        const float g = __expf(l[e] - m) / s * 0.0625f;   // gate * 1/R
        union { unsigned short u[16]; uint4 q[2]; } pk;
#pragma unroll
        for (int jj = 0; jj < 16; ++jj) pk.u[jj] = f2bf(g * Tsm[tok][e * 16 + jj]);
        uint4* dst = (uint4*)(Xcat + (size_t)(row0 + tok) * XLD + 1024 + e * 16);
        dst[0] = pk.q[0]; dst[1] = pk.q[1];
    }
}

// ---- GEMM2: out = Xcat @ Wcat^T (K=1152), 128x64, grid 512, T4 pipeline ----
__global__ __launch_bounds__(256) void k_gemm2(const __hip_bfloat16* __restrict__ A,
                                               const __hip_bfloat16* __restrict__ B,
                                               float* __restrict__ out) {
    __shared__ char smem[49152];                   // A: 2x16KB @0; B: 2x8KB @32768
    const int b = blockIdx.x;
    const int xcd = b & 7, j = b >> 3;
    const int bx = xcd * 4 + (j & 3), by = j >> 2;
    const int row0 = bx * 128, col0 = by * 64;

    const int t = threadIdx.x, lane = t & 63, wid = t >> 6;
    const int wr = wid >> 1, wc = wid & 1;
    const int l7 = lane & 7, l8 = lane >> 3, l15 = lane & 15, l16 = lane >> 4;
    const int scol = ((l7 ^ l8) << 3);

    f32x4 zf = {0.f, 0.f, 0.f, 0.f};
    f32x4 acc[4][2];
#pragma unroll
    for (int m = 0; m < 4; ++m)
#pragma unroll
        for (int n = 0; n < 2; ++n) acc[m][n] = zf;

    int aoff[4], boff[2], sw[2];
#pragma unroll
    for (int m = 0; m < 4; ++m) aoff[m] = (wr * 64 + m * 16 + l15) * 128;
#pragma unroll
    for (int n = 0; n < 2; ++n) boff[n] = (wc * 32 + n * 16 + l15) * 128;
#pragma unroll
    for (int ks = 0; ks < 2; ++ks) sw[ks] = (((ks * 4 + l16) ^ l7) << 4);

#define G2_STAGE(buf, kt)                                                      \
    {                                                                          \
        const int k0_ = (kt) << 6;                                             \
        _Pragma("unroll")                                                      \
        for (int i = 0; i < 4; ++i) {                                          \
            int ci = wid * 4 + i;                                              \
            gload16(A + (size_t)(row0 + ci * 8 + l8) * XLD + k0_ + scol,       \
                    smem + (buf) * 16384 + ci * 1024);                         \
        }                                                                      \
        _Pragma("unroll")                                                      \
        for (int i = 0; i < 2; ++i) {                                          \
            int cj = wid * 2 + i;                                              \
            gload16(B + (size_t)(col0 + cj * 8 + l8) * KTOT + k0_ + scol,      \
                    smem + 32768 + (buf) * 8192 + cj * 1024);                  \
        }                                                                      \
    }

#define G2_COMP(buf)                                                           \
    {                                                                          \
        const char* Ab = smem + (buf) * 16384;                                 \
        const char* Bb = smem + 32768 + (buf) * 8192;                          \
        _Pragma("unroll")                                                      \
        for (int ks = 0; ks < 2; ++ks) {                                       \
            short8 af[4], bf[2];                                               \
            _Pragma("unroll")                                                  \
            for (int m = 0; m < 4; ++m)                                        \
                af[m] = *(const short8*)(Ab + aoff[m] + sw[ks]);               \
            _Pragma("unroll")                                                  \
            for (int n = 0; n < 2; ++n)                                        \
                bf[n] = *(const short8*)(Bb + boff[n] + sw[ks]);               \
            _Pragma("unroll")                                                  \
            for (int m = 0; m < 4; ++m)                                        \
                _Pragma("unroll")                                              \
                for (int n = 0; n < 2; ++n)                                    \
                    acc[m][n] = __builtin_amdgcn_mfma_f32_16x16x32_bf16(       \
                        af[m], bf[n], acc[m][n], 0, 0, 0);                     \
        }                                                                      \
    }

    G2_STAGE(0, 0);
    int cur = 0;
    for (int kt = 0; kt < 18; ++kt) {
        if (kt < 17) {
            G2_STAGE(cur ^ 1, kt + 1);             // issue next tile (stays in flight)
            asm volatile("s_waitcnt vmcnt(6)" ::: "memory");   // drain current only
        } else {
            asm volatile("s_waitcnt vmcnt(0)" ::: "memory");
        }
        __builtin_amdgcn_s_barrier();
        G2_COMP(cur);
        __builtin_amdgcn_s_barrier();              // all reads done before restage
        cur ^= 1;
    }

#pragma unroll
    for (int m = 0; m < 4; ++m)
#pragma unroll
        for (int n = 0; n < 2; ++n)
#pragma unroll
            for (int jj = 0; jj < 4; ++jj)
                out[(size_t)(row0 + wr * 64 + m * 16 + l16 * 4 + jj) * DOUT
                    + col0 + wc * 32 + n * 16 + l15] = acc[m][n][jj];
#undef G2_STAGE
#undef G2_COMP
}

extern "C" void kernel_launch(void* const* d_in, const int* in_sizes, int n_in,
                              void* d_out, int out_size, void* d_ws, size_t ws_size,
                              hipStream_t stream) {
    const float* x      = (const float*)d_in[0];   // (4,1024,1024)
    const float* weight = (const float*)d_in[1];   // (1024,1024)
    const float* gate_w = (const float*)d_in[2];   // (8,1024)
    const float* lora_U = (const float*)d_in[3];   // (8,16,1024)
    const float* lora_V = (const float*)d_in[4];   // (8,1024,16)
    float* out = (float*)d_out;

    char* ws = (char*)d_ws;
    __hip_bfloat16* Xcat = (__hip_bfloat16*)ws;                        // 4096x1152 (9.44 MB)
    __hip_bfloat16* Ucat = (__hip_bfloat16*)(ws + 9437184);            // 192x1024  (0.39 MB)
    __hip_bfloat16* Wcat = (__hip_bfloat16*)(ws + 9437184 + 393216);   // 1024x1152 (2.36 MB)

    k_cvtuw<<<2720, 256, 0, stream>>>(x, lora_U, gate_w, weight, lora_V, Xcat, Ucat, Wcat);
    k_gemm1f<<<256, 256, 0, stream>>>(Xcat, Ucat, Xcat);
    k_gemm2<<<512, 256, 0, stream>>>(Xcat, Wcat, out);
}